// Round 10
// baseline (201.272 us; speedup 1.0000x reference)
//
#include <hip/hip_runtime.h>
#include <math.h>

// TopKMoEGate: T = 16384, D = 1024, E = 64, topK = 2.
// Round 10: r9's fused structure + 8-way intra-block split-K for TLP.
//  - r9 lesson: fused kernel was latency-bound (MfmaUtil 9.7%, VGPR=60:
//    compiler serialized B loads into tiny vmcnt batches; 16 waves/CU of
//    one generation couldn't fill ~200-cyc L2 stalls).
//  - Fix: block = 512 threads = 8 waves, each wave does K/8 (2 chunks) for
//    the same 16 tokens -> 8192 waves = 32 waves/CU (100% occupancy at
//    VGPR<=64, which launch_bounds(512,8) enforces; r9 body was 60 VGPRs
//    with twice the unroll). Per-wave latency rounds halve (4 vs 8);
//    8 waves/SIMD fill each ~200-cyc stall.
//  - Partials exchanged via 32 KB LDS, one barrier, fused r3-verified
//    butterfly top-2 + sparse softmax epilogue (2 tokens per wave).
//  - 3-slice bf16 split (r4..r9-verified numerics), B from L2-resident
//    pre-permuted wimg, A prefetch distance 1 chunk.

#define DDIM 1024
#define NEXP 64
#define NTOK 16384
#define WPB 8                 // waves per block (split-K ways)
#define CPW 2                 // k64-chunks per wave (K/8 = 128)
#define CHUNK_SH 12288        // shorts per k64 chunk (1536 units * 8)

typedef float f4 __attribute__((ext_vector_type(4)));
typedef short s8 __attribute__((ext_vector_type(8)));
typedef unsigned int u32;

static __device__ __forceinline__ void split3(float f, short& h, short& m, short& l) {
    const u32 uf = __float_as_uint(f);
    h = (short)(uf >> 16);
    const float r1 = f - __uint_as_float(uf & 0xffff0000u);
    const u32 u1 = __float_as_uint(r1);
    m = (short)(u1 >> 16);
    const float r2 = r1 - __uint_as_float(u1 & 0xffff0000u);
    l = (short)(__float_as_uint(r2) >> 16);
}

// ---- kernel 0: slice gate_w into 3 bf16 levels, lane-ordered image ----
// unit16 U(c,kk,lv,t,q,m) = c*1536 + (kk*3+lv)*256 + t*64 + (q*16+m),
// holding w[e=t*16+m][k0..k0+7], k0 = c*64 + kk*32 + q*8.  (r5-verified)
__global__ __launch_bounds__(256)
void w_prep(const float* __restrict__ gw, short* __restrict__ wimg) {
    const int uid = blockIdx.x * 256 + threadIdx.x;   // 8192 threads
    const int c   = uid >> 9;
    const int kk  = (uid >> 8) & 1;
    const int e   = (uid >> 2) & 63;
    const int q   = uid & 3;
    const int k0  = c * 64 + kk * 32 + q * 8;
    const float* src = gw + (size_t)e * DDIM + k0;
    s8 hv, mv, lv;
    #pragma unroll
    for (int j = 0; j < 8; ++j) {
        short h, m, l;
        split3(src[j], h, m, l);
        hv[j] = h; mv[j] = m; lv[j] = l;
    }
    const size_t base = (size_t)c * 1536 + (kk * 3) * 256
                      + (e >> 4) * 64 + q * 16 + (e & 15);
    *(s8*)(wimg + (base      ) * 8) = hv;
    *(s8*)(wimg + (base + 256) * 8) = mv;
    *(s8*)(wimg + (base + 512) * 8) = lv;
}

// ---- kernel 1: fused GEMM + block reduce + noisy top-2 + softmax ----
static __device__ __forceinline__ bool bt(float av, int ai, float bv, int bi) {
    return av > bv || (av == bv && ai < bi);   // jax.lax.top_k order
}

__global__ __launch_bounds__(512, 8)
void moe_fused(const float* __restrict__ x,
               const short* __restrict__ wimg,
               const float* __restrict__ nwt,
               const float* __restrict__ noise,
               float* __restrict__ out_w,
               float* __restrict__ out_i)
{
    __shared__ float red[WPB][16][NEXP];        // 32 KB partial exchange

    const int tid  = threadIdx.x;
    const int lane = tid & 63;
    const int wv   = tid >> 6;                  // K-eighth index 0..7
    const int m    = lane & 15;                 // A-frag row / C col
    const int q    = lane >> 4;                 // k-octet quad / C row-quad
    const int tokBase = blockIdx.x * 16;

    const float* xrow = x + (size_t)(tokBase + m) * DDIM + wv * (CPW * 64) + q * 8;

    f4 acc0[4], acc1[4];
    #pragma unroll
    for (int t = 0; t < 4; ++t) { acc0[t] = (f4)0.f; acc1[t] = (f4)0.f; }

    // A chunk-0 loads in flight immediately
    f4 As[4];
    As[0] = *(const f4*)(xrow);
    As[1] = *(const f4*)(xrow + 4);
    As[2] = *(const f4*)(xrow + 32);
    As[3] = *(const f4*)(xrow + 36);

    #pragma unroll
    for (int cc = 0; cc < CPW; ++cc) {
        const short* cb = wimg + (size_t)(wv * CPW + cc) * CHUNK_SH;

        // convert current A chunk -> 3-level bf16 frags
        s8 ah[2], am[2], al[2];
        const float* sv = (const float*)&As[0];
        #pragma unroll
        for (int kk = 0; kk < 2; ++kk)
            #pragma unroll
            for (int j = 0; j < 8; ++j) {
                short h, mm, l;
                split3(sv[kk * 8 + j], h, mm, l);
                ah[kk][j] = h; am[kk][j] = mm; al[kk][j] = l;
            }

        // prefetch next A chunk (latency covered by this chunk's MFMAs)
        if (cc + 1 < CPW) {
            const float* s = xrow + (cc + 1) * 64;
            As[0] = *(const f4*)(s);
            As[1] = *(const f4*)(s + 4);
            As[2] = *(const f4*)(s + 32);
            As[3] = *(const f4*)(s + 36);
        }

        #pragma unroll
        for (int kk = 0; kk < 2; ++kk) {
            #pragma unroll
            for (int t = 0; t < 4; ++t) {
                const int pb = (kk * 3) * 256 + t * 64 + lane;
                const s8 bh = *(const s8*)(cb + (size_t)(pb      ) * 8);
                const s8 bm = *(const s8*)(cb + (size_t)(pb + 256) * 8);
                const s8 bl = *(const s8*)(cb + (size_t)(pb + 512) * 8);
                acc0[t] = __builtin_amdgcn_mfma_f32_16x16x32_bf16(ah[kk], bh, acc0[t], 0, 0, 0);
                acc1[t] = __builtin_amdgcn_mfma_f32_16x16x32_bf16(ah[kk], bm, acc1[t], 0, 0, 0);
                acc1[t] = __builtin_amdgcn_mfma_f32_16x16x32_bf16(am[kk], bh, acc1[t], 0, 0, 0);
                acc1[t] = __builtin_amdgcn_mfma_f32_16x16x32_bf16(ah[kk], bl, acc1[t], 0, 0, 0);
                acc1[t] = __builtin_amdgcn_mfma_f32_16x16x32_bf16(am[kk], bm, acc1[t], 0, 0, 0);
                acc1[t] = __builtin_amdgcn_mfma_f32_16x16x32_bf16(al[kk], bh, acc1[t], 0, 0, 0);
            }
        }
    }

    // partial exchange: C row = q*4+r (token), col = m + 16t (expert)
    #pragma unroll
    for (int t = 0; t < 4; ++t)
        #pragma unroll
        for (int r = 0; r < 4; ++r)
            red[wv][q * 4 + r][m + 16 * t] = acc0[t][r] + acc1[t][r];

    __syncthreads();

    // fused epilogue: wave wv handles tokens wv*2, wv*2+1; lane = expert
    const float nw = nwt[lane];
    #pragma unroll
    for (int r = 0; r < 2; ++r) {
        const int lt  = wv * 2 + r;
        const int tok = tokBase + lt;
        const float sum = ((red[0][lt][lane] + red[1][lt][lane])
                         + (red[2][lt][lane] + red[3][lt][lane]))
                        + ((red[4][lt][lane] + red[5][lt][lane])
                         + (red[6][lt][lane] + red[7][lt][lane]));
        const float ln = fmaf(noise[(size_t)tok * NEXP + lane], nw, sum);

        // top-1 then top-2 butterfly (r3-verified, jax tie-break)
        float v1 = ln; int i1 = lane;
        #pragma unroll
        for (int off = 32; off > 0; off >>= 1) {
            const float vo = __shfl_xor(v1, off, 64);
            const int   io = __shfl_xor(i1, off, 64);
            if (bt(vo, io, v1, i1)) { v1 = vo; i1 = io; }
        }
        float v2 = (lane == i1) ? -3.4e38f : ln; int i2 = lane;
        #pragma unroll
        for (int off = 32; off > 0; off >>= 1) {
            const float vo = __shfl_xor(v2, off, 64);
            const int   io = __shfl_xor(i2, off, 64);
            if (bt(vo, io, v2, i2)) { v2 = vo; i2 = io; }
        }

        const float d   = expf(v2 - v1);
        const float inv = 1.f / (1.f + d);
        const float wgt = (lane == i1) ? inv : ((lane == i2) ? d * inv : 0.f);
        out_w[(size_t)tok * NEXP + lane] = wgt;
        if (lane == 0) {
            out_i[(size_t)tok * 2]     = (float)i1;
            out_i[(size_t)tok * 2 + 1] = (float)i2;
        }
    }
}

extern "C" void kernel_launch(void* const* d_in, const int* in_sizes, int n_in,
                              void* d_out, int out_size, void* d_ws, size_t ws_size,
                              hipStream_t stream) {
    const float* x     = (const float*)d_in[0];
    const float* gw    = (const float*)d_in[1];
    const float* nwt   = (const float*)d_in[2];
    const float* noise = (const float*)d_in[3];
    float* out_w = (float*)d_out;                        // [NTOK][64]
    float* out_i = (float*)d_out + (size_t)NTOK * NEXP;  // [NTOK][2] as float
    short* wimg  = (short*)d_ws;                         // 384 KB image

    hipLaunchKernelGGL(w_prep, dim3(32), dim3(256), 0, stream, gw, wimg);
    hipLaunchKernelGGL(moe_fused, dim3(NTOK / 16), dim3(512), 0, stream,
                       x, wimg, nwt, noise, out_w, out_i);
}